// Round 10
// baseline (120.651 us; speedup 1.0000x reference)
//
#include <hip/hip_runtime.h>
#include <hip/hip_bf16.h>
#include <stdint.h>

// KANExpert: out[b,j] = sum_{i,g} basis(x[b,i])[g] * coeff[i,j,g] * scaling[i,j]
// == GEMM M=4096(batch) N=512(out) K=4096(=512 in_dim * 8 basis), bf16 MFMA.
//
// R10: R6 vs R8/R9 comparison shows fused-basis LDS machinery halves staging
// throughput (34 -> 13 B/cyc/CU). Key insight: mfma_16x16x32 A-operand layout
// A[m=lane&15][k=quad*8+j] means one lane's short8 = one input-dim's 8 basis
// values -> af = basis_pack8(x[row][kt*8+kk*4+quad]) DIRECTLY IN REGISTERS.
// A never touches LDS. Block = 128x64 (tall M is free since A is computed),
// LDS = B-ring only (4 x 8 KB). 256 blocks (1/CU), grid b = r + 32*c so
// XCD = r%8 (x-slice fetched once). Barrier + manual vm(12) publishes B.

#define BATCH   4096
#define IN_DIM  512
#define OUT_DIM 512
#define KDIM    (IN_DIM * 8)   // 4096
#define NKT     (KDIM / 64)    // 64 K-tiles

typedef short short8 __attribute__((ext_vector_type(8)));
typedef float f32x4  __attribute__((ext_vector_type(4)));

// s_waitcnt simm16 (gfx9): vmcnt[3:0] | expcnt[6:4] | lgkmcnt[11:8]
#define W_VM12_LG0 0x07C

// float -> bf16 bits, round-to-nearest-even (prep only)
__device__ __forceinline__ unsigned int f2bf(float f) {
  union { float f; unsigned int u; } v; v.f = f;
  unsigned int r = v.u + 0x7FFFu + ((v.u >> 16) & 1u);
  return r >> 16;
}

// All 8 basis values of one (b,i) as bf16 short8 (== MFMA A-frag for that i).
// Uniform cubic B-spline, h=0.4: m = min((int)(x*2.5+2.5),4), u in [0,1];
// window w0..w3 placed at slots m-3..m via branchless 64-bit shift.
__device__ __forceinline__ short8 basis_pack8(float xv) {
  float t = __builtin_fmaf(xv, 2.5f, 2.5f);
  int m = (int)t;                       // t >= 0 -> trunc == floor
  m = m > 4 ? 4 : m;
  float u  = t - (float)m;
  float u2 = u * u, u3 = u2 * u, om = 1.0f - u;
  float om2 = om * om;
  float w0 = om2 * om * (1.0f / 6.0f);
  float w1 = __builtin_fmaf(u3, 0.5f, __builtin_fmaf(u2, -1.0f, 2.0f / 3.0f));
  float s  = (u2 - u3) + u;
  float w2 = __builtin_fmaf(s, 0.5f, 1.0f / 6.0f);
  float w3 = u3 * (1.0f / 6.0f);
  unsigned d0 = __builtin_amdgcn_perm(__float_as_uint(w1), __float_as_uint(w0), 0x07060302u);
  unsigned d1 = __builtin_amdgcn_perm(__float_as_uint(w3), __float_as_uint(w2), 0x07060302u);
  uint64_t wp = ((uint64_t)d1 << 32) | d0;
  int sh = m * 16 - 48;                 // {-48,-32,-16,0,16}
  uint64_t lo = (sh >= 0) ? (wp << sh) : (wp >> (-sh));
  unsigned hi = (sh > 0) ? (unsigned)(wp >> (64 - sh)) : 0u;
  union { unsigned d[4]; short8 s8; } r;
  r.d[0] = (unsigned)lo; r.d[1] = (unsigned)(lo >> 32); r.d[2] = hi; r.d[3] = 0u;
  return r.s8;
}

__device__ __forceinline__ void async_load16(const void* g, void* l) {
  __builtin_amdgcn_global_load_lds(
      (__attribute__((address_space(1))) void*)(uintptr_t)g,
      (__attribute__((address_space(3))) void*)(unsigned int)(uintptr_t)l,
      16, 0, 0);
}

// ---- precompute W^T: Wt[j*4096 + i*8 + g] = bf16(coeff[i,j,g]*scaling[i,j])
__global__ void kan_prep(const float* __restrict__ coeff,
                         const float* __restrict__ scaling,
                         unsigned short* __restrict__ Wt) {
  int idx = blockIdx.x * 256 + threadIdx.x;  // i*512 + j
  int i = idx >> 9, j = idx & 511;
  float s = scaling[idx];
  const float4* cp = reinterpret_cast<const float4*>(coeff) + (size_t)idx * 2;
  float4 c0 = cp[0], c1 = cp[1];
  short8 h;
  h[0] = (short)f2bf(c0.x * s); h[1] = (short)f2bf(c0.y * s);
  h[2] = (short)f2bf(c0.z * s); h[3] = (short)f2bf(c0.w * s);
  h[4] = (short)f2bf(c1.x * s); h[5] = (short)f2bf(c1.y * s);
  h[6] = (short)f2bf(c1.z * s); h[7] = (short)f2bf(c1.w * s);
  *reinterpret_cast<short8*>(Wt + (size_t)j * KDIM + i * 8) = h;
}

// ---- register-A 128x64x64 GEMM, depth-4 B-ring ---------------------------
// 256 thr = 4 waves; wave w owns rows w*32..w*32+31 (2 mt of 16) x all 64
// cols (4 nt). A-frags computed in registers from x (prefetched 2 tiles
// ahead). B staged via global_load_lds into XOR-swizzled ring (proven
// 0-conflict). Per iter k: wait vm(12) lgkm(0); barrier (B(k) published);
// issueB(k+3); load x(k+2); basis+MFMA on stage k%4.
__global__ __launch_bounds__(256, 2)
void kan_gemm_r(const float* __restrict__ x,
                const unsigned short* __restrict__ Wt,
                float* __restrict__ out) {
  __shared__ unsigned short Bs[4][64 * 64];   // 4 x 8 KB

  const int tid  = threadIdx.x;
  const int lane = tid & 63;
  const int wid  = tid >> 6;
  const int ln = lane & 15, quad = lane >> 4;

  const int b    = blockIdx.x;
  const int row0 = (b & 31) * 128;          // XCD = b%8 = rowtile%8
  const int col0 = (b >> 5) * 64;

  f32x4 acc[2][4] = {};                     // [mt][nt]

  // B staging addresses (wave-uniform LDS dest + lane-contiguous gather)
  const int lr = lane >> 3;
  const int cg = (lane & 7) ^ lr;
  const unsigned short* bP0 = Wt + (size_t)(col0 + wid * 16 + lr) * KDIM + cg * 8;
  const unsigned short* bP1 = bP0 + (size_t)8 * KDIM;

  // x pointers: lane reads x[row0 + wid*32 + mt*16 + ln][kt*8 + kk*4 + quad]
  const float* xP0 = x + (size_t)(row0 + wid * 32 + ln) * IN_DIM + quad;
  const float* xP1 = xP0 + (size_t)16 * IN_DIM;

  // B-frag LDS offsets (iter-invariant; stage base folds to immediate)
  int boff[2][4];
#pragma unroll
  for (int kk = 0; kk < 2; ++kk)
#pragma unroll
    for (int nt = 0; nt < 4; ++nt) {
      const int c = nt * 16 + ln;
      boff[kk][nt] = c * 64 + (((kk * 4 + quad) ^ (c & 7)) * 8);
    }

  auto issueB = [&](int kt, int st) {
    const int k0 = kt * 64;
    async_load16(bP0 + k0, &Bs[st][(wid * 16) * 64]);
    async_load16(bP1 + k0, &Bs[st][(wid * 16 + 8) * 64]);
  };

  // x prefetch buffers: [parity][mt][kk]; tile t lives in buf t&1
  float xa[2][2][2];
  auto loadx = [&](int t, int buf) {
#pragma unroll
    for (int kk = 0; kk < 2; ++kk) {
      xa[buf][0][kk] = xP0[t * 8 + kk * 4];
      xa[buf][1][kk] = xP1[t * 8 + kk * 4];
    }
  };

  // ---- prologue: B0; B1; x0; B2; x1  (vmcnt stream = steady pattern) -----
  issueB(0, 0);
  issueB(1, 1);
  loadx(0, 0);
  issueB(2, 2);
  loadx(1, 1);

  // ---- main loop: 16 groups x 4 (ring stage compile-time) ----------------
  // At iter-k wait: outstanding <= B2(k),x4(k-?),B2(k+1),x4(k),B2(k+2),x4(k+1)
  // -> vm(12) retires B2(k). lgkm(0) free (no ds_writes; reads drained).
  for (int g = 0; g < 16; ++g) {
#pragma unroll
    for (int s = 0; s < 4; ++s) {
      const int kt = g * 4 + s;            // kt & 3 == s
      __builtin_amdgcn_s_waitcnt(W_VM12_LG0);
      __builtin_amdgcn_s_barrier();
      // snapshot current x (buf kt&1) before reloading that buffer
      float cur[2][2];
#pragma unroll
      for (int mt = 0; mt < 2; ++mt)
#pragma unroll
        for (int kk = 0; kk < 2; ++kk) cur[mt][kk] = xa[s & 1][mt][kk];
      const int kb = (kt + 3 < NKT) ? kt + 3 : NKT - 1;
      const int kx = (kt + 2 < NKT) ? kt + 2 : NKT - 1;
      issueB(kb, (s + 3) & 3);
      loadx(kx, s & 1);
      // basis (registers) + MFMA on stage s
#pragma unroll
      for (int kk = 0; kk < 2; ++kk) {
        short8 af0 = basis_pack8(cur[0][kk]);
        short8 af1 = basis_pack8(cur[1][kk]);
#pragma unroll
        for (int nt = 0; nt < 4; ++nt) {
          short8 bfr = *reinterpret_cast<const short8*>(&Bs[s][boff[kk][nt]]);
          acc[0][nt] = __builtin_amdgcn_mfma_f32_16x16x32_bf16(af0, bfr, acc[0][nt], 0, 0, 0);
          acc[1][nt] = __builtin_amdgcn_mfma_f32_16x16x32_bf16(af1, bfr, acc[1][nt], 0, 0, 0);
        }
      }
    }
  }

  // C/D layout: col = lane&15, row = quad*4 + reg  (m89/m91-verified)
#pragma unroll
  for (int mt = 0; mt < 2; ++mt)
#pragma unroll
    for (int nt = 0; nt < 4; ++nt) {
      const int col = col0 + nt * 16 + ln;
#pragma unroll
      for (int r = 0; r < 4; ++r) {
        const int row = row0 + wid * 32 + mt * 16 + quad * 4 + r;
        out[(size_t)row * OUT_DIM + col] = acc[mt][nt][r];
      }
    }
}

// ---- fallback (no ws): on-the-fly staging, 64-tile, direct store ---------
__global__ __launch_bounds__(256, 2)
void kan_gemm_fb(const float* __restrict__ x, const float* __restrict__ coeff,
                 const float* __restrict__ scaling, float* __restrict__ out) {
  __shared__ unsigned short As[64 * 64];
  __shared__ unsigned short Bs[64 * 64];

  const int tid  = threadIdx.x;
  const int lane = tid & 63;
  const int wid  = tid >> 6;
  const int wm = wid >> 1, wn = wid & 1;
  const int ln = lane & 15, quad = lane >> 4;
  const int row0 = blockIdx.y * 64;
  const int col0 = blockIdx.x * 64;

  f32x4 acc[2][2] = {};

  for (int kt = 0; kt < KDIM / 64; ++kt) {
#pragma unroll
    for (int pp = 0; pp < 2; ++pp) {
      const int p  = tid + pp * 256;
      const int rn = p & 63;
      const int il = p >> 6;
      const int sw = ((il ^ (rn & 7)) * 8);
      short8 ha = basis_pack8(x[(size_t)(row0 + rn) * IN_DIM + kt * 8 + il]);
      *reinterpret_cast<short8*>(&As[rn * 64 + sw]) = ha;
      const float* cbase = coeff + (size_t)(kt * 8 + il) * 4096 + (size_t)(col0 + rn) * 8;
      float4 c0 = reinterpret_cast<const float4*>(cbase)[0];
      float4 c1 = reinterpret_cast<const float4*>(cbase)[1];
      float s = scaling[(size_t)(kt * 8 + il) * OUT_DIM + col0 + rn];
      short8 hb;
      hb[0] = (short)f2bf(c0.x * s); hb[1] = (short)f2bf(c0.y * s);
      hb[2] = (short)f2bf(c0.z * s); hb[3] = (short)f2bf(c0.w * s);
      hb[4] = (short)f2bf(c1.x * s); hb[5] = (short)f2bf(c1.y * s);
      hb[6] = (short)f2bf(c1.z * s); hb[7] = (short)f2bf(c1.w * s);
      *reinterpret_cast<short8*>(&Bs[rn * 64 + sw]) = hb;
    }
    __syncthreads();
#pragma unroll
    for (int kk = 0; kk < 2; ++kk) {
      short8 af[2], bfr[2];
#pragma unroll
      for (int mt = 0; mt < 2; ++mt) {
        const int r  = wm * 32 + mt * 16 + ln;
        const int pc = (kk * 4 + quad) ^ (r & 7);
        af[mt] = *reinterpret_cast<const short8*>(&As[r * 64 + pc * 8]);
      }
#pragma unroll
      for (int nt = 0; nt < 2; ++nt) {
        const int c  = wn * 32 + nt * 16 + ln;
        const int pc = (kk * 4 + quad) ^ (c & 7);
        bfr[nt] = *reinterpret_cast<const short8*>(&Bs[c * 64 + pc * 8]);
      }
#pragma unroll
      for (int mt = 0; mt < 2; ++mt)
#pragma unroll
        for (int nt = 0; nt < 2; ++nt)
          acc[mt][nt] = __builtin_amdgcn_mfma_f32_16x16x32_bf16(af[mt], bfr[nt], acc[mt][nt], 0, 0, 0);
    }
    __syncthreads();
  }
#pragma unroll
  for (int mt = 0; mt < 2; ++mt)
#pragma unroll
    for (int nt = 0; nt < 2; ++nt) {
      const int col = col0 + wn * 32 + nt * 16 + ln;
#pragma unroll
      for (int r = 0; r < 4; ++r) {
        const int row = row0 + wm * 32 + mt * 16 + quad * 4 + r;
        out[(size_t)row * OUT_DIM + col] = acc[mt][nt][r];
      }
    }
}

// ---- launch ------------------------------------------------------------
extern "C" void kernel_launch(void* const* d_in, const int* in_sizes, int n_in,
                              void* d_out, int out_size, void* d_ws, size_t ws_size,
                              hipStream_t stream) {
  const float* x       = (const float*)d_in[0];
  const float* coeff   = (const float*)d_in[1];
  const float* scaling = (const float*)d_in[2];
  float* out = (float*)d_out;

  const size_t needW = (size_t)OUT_DIM * KDIM * 2;   // 4 MB bf16 W^T

  if (ws_size >= needW) {
    unsigned short* Wt = (unsigned short*)d_ws;
    kan_prep<<<(IN_DIM * OUT_DIM) / 256, 256, 0, stream>>>(coeff, scaling, Wt);
    kan_gemm_r<<<(BATCH / 128) * (OUT_DIM / 64), 256, 0, stream>>>(x, Wt, out);
  } else {
    kan_gemm_fb<<<dim3(OUT_DIM / 64, BATCH / 64), 256, 0, stream>>>(x, coeff, scaling, out);
  }
}

// Round 11
// 102.488 us; speedup vs baseline: 1.1772x; 1.1772x over previous
//
#include <hip/hip_runtime.h>
#include <hip/hip_bf16.h>
#include <stdint.h>

// KANExpert: out[b,j] = sum_{i,g} basis(x[b,i])[g] * coeff[i,j,g] * scaling[i,j]
// == GEMM M=4096(batch) N=512(out) K=4096(=512 in_dim * 8 basis), bf16 MFMA.
//
// R11 = union of everything proven: register-A fragments (R10, HW-verified
// mapping), all-DMA VM stream + ring + raw barrier + manual vmcnt (R6/R8/R9,
// proven protocol), 8 waves/CU (R9; R10's 4 waves/CU was the regression).
// Block 64x64, 4 waves of 16rows x 64cols (VALU-minimal: 2 basis/wave-iter).
// Per iter k: wait vm(8); barrier; ds_read x(k+1); issueB(k+3); issueX(k+4);
// MFMA(k) [8, from afc regs + Bs ring]; basis(k+1) -> afn regs. No ds_writes
// -> no lgkm coupling. Uniform DMA counts via clamped tail issues.

#define BATCH   4096
#define IN_DIM  512
#define OUT_DIM 512
#define KDIM    (IN_DIM * 8)   // 4096
#define NKT     (KDIM / 64)    // 64 K-tiles

typedef short short8 __attribute__((ext_vector_type(8)));
typedef float f32x4  __attribute__((ext_vector_type(4)));

// s_waitcnt simm16 (gfx9): vmcnt[3:0] | expcnt[6:4]=7 | lgkmcnt[11:8]=15 (dc)
#define W_VM8  0xF78
#define W_VM12 0xF7C

// float -> bf16 bits, round-to-nearest-even (prep only)
__device__ __forceinline__ unsigned int f2bf(float f) {
  union { float f; unsigned int u; } v; v.f = f;
  unsigned int r = v.u + 0x7FFFu + ((v.u >> 16) & 1u);
  return r >> 16;
}

// All 8 basis values of one (b,i) as bf16 short8 == MFMA A-frag (HW-verified
// R10). Uniform cubic B-spline, h=0.4: m=min((int)(x*2.5+2.5),4), u in [0,1];
// window w0..w3 placed at slots m-3..m via branchless 64-bit shift.
__device__ __forceinline__ short8 basis_pack8(float xv) {
  float t = __builtin_fmaf(xv, 2.5f, 2.5f);
  int m = (int)t;
  m = m > 4 ? 4 : m;
  float u  = t - (float)m;
  float u2 = u * u, u3 = u2 * u, om = 1.0f - u;
  float om2 = om * om;
  float w0 = om2 * om * (1.0f / 6.0f);
  float w1 = __builtin_fmaf(u3, 0.5f, __builtin_fmaf(u2, -1.0f, 2.0f / 3.0f));
  float s  = (u2 - u3) + u;
  float w2 = __builtin_fmaf(s, 0.5f, 1.0f / 6.0f);
  float w3 = u3 * (1.0f / 6.0f);
  unsigned d0 = __builtin_amdgcn_perm(__float_as_uint(w1), __float_as_uint(w0), 0x07060302u);
  unsigned d1 = __builtin_amdgcn_perm(__float_as_uint(w3), __float_as_uint(w2), 0x07060302u);
  uint64_t wp = ((uint64_t)d1 << 32) | d0;
  int sh = m * 16 - 48;
  uint64_t lo = (sh >= 0) ? (wp << sh) : (wp >> (-sh));
  unsigned hi = (sh > 0) ? (unsigned)(wp >> (64 - sh)) : 0u;
  union { unsigned d[4]; short8 s8; } r;
  r.d[0] = (unsigned)lo; r.d[1] = (unsigned)(lo >> 32); r.d[2] = hi; r.d[3] = 0u;
  return r.s8;
}

__device__ __forceinline__ void async_load16(const void* g, void* l) {
  __builtin_amdgcn_global_load_lds(
      (__attribute__((address_space(1))) void*)(uintptr_t)g,
      (__attribute__((address_space(3))) void*)(unsigned int)(uintptr_t)l,
      16, 0, 0);
}
__device__ __forceinline__ void async_load4(const void* g, void* l) {
  __builtin_amdgcn_global_load_lds(
      (__attribute__((address_space(1))) void*)(uintptr_t)g,
      (__attribute__((address_space(3))) void*)(unsigned int)(uintptr_t)l,
      4, 0, 0);
}

// ---- precompute W^T: Wt[j*4096 + i*8 + g] = bf16(coeff[i,j,g]*scaling[i,j])
__global__ void kan_prep(const float* __restrict__ coeff,
                         const float* __restrict__ scaling,
                         unsigned short* __restrict__ Wt) {
  int idx = blockIdx.x * 256 + threadIdx.x;  // i*512 + j
  int i = idx >> 9, j = idx & 511;
  float s = scaling[idx];
  const float4* cp = reinterpret_cast<const float4*>(coeff) + (size_t)idx * 2;
  float4 c0 = cp[0], c1 = cp[1];
  short8 h;
  h[0] = (short)f2bf(c0.x * s); h[1] = (short)f2bf(c0.y * s);
  h[2] = (short)f2bf(c0.z * s); h[3] = (short)f2bf(c0.w * s);
  h[4] = (short)f2bf(c1.x * s); h[5] = (short)f2bf(c1.y * s);
  h[6] = (short)f2bf(c1.z * s); h[7] = (short)f2bf(c1.w * s);
  *reinterpret_cast<short8*>(Wt + (size_t)j * KDIM + i * 8) = h;
}

// ---- register-A 64x64x64 GEMM, depth-4 all-DMA rings ---------------------
// 256 thr = 4 waves; wave w: rows w*16..w*16+15 (m = ln), cols 0..63 (4 nt).
// A-frag(kt,kk) = basis_pack8(x[row0+w*16+ln][kt*8+kk*4+quad]) in registers.
// Grid 512, 1-D: row-tile = b%64 (XCD = b%8 -> x/out L2-pinned), col = b/64.
__global__ __launch_bounds__(256, 2)
void kan_gemm_ra(const float* __restrict__ x,
                 const unsigned short* __restrict__ Wt,
                 float* __restrict__ out) {
  __shared__ unsigned short Bs[4][64 * 64];   // 4 x 8 KB
  __shared__ float          Xs[4][512];       // 4 x 2 KB

  const int tid  = threadIdx.x;
  const int lane = tid & 63;
  const int wid  = tid >> 6;
  const int ln = lane & 15, quad = lane >> 4;

  const int b    = blockIdx.x;
  const int row0 = (b & 63) * 64;
  const int col0 = (b >> 6) * 64;

  f32x4 acc[4] = {};                          // [nt]

  // B staging (proven): wave-uniform LDS dest + XOR-swizzled gather
  const int lr = lane >> 3;
  const int cg = (lane & 7) ^ lr;
  const unsigned short* bP0 = Wt + (size_t)(col0 + wid * 16 + lr) * KDIM + cg * 8;
  const unsigned short* bP1 = bP0 + (size_t)8 * KDIM;

  // X staging (proven R8/R9): 512 floats per tile, lane-linear DMA
  const int f0 = wid * 128 + lane;
  const int f1 = f0 + 64;
  const float* xG0 = x + (size_t)(row0 + (f0 >> 3)) * IN_DIM + (f0 & 7);
  const float* xG1 = x + (size_t)(row0 + (f1 >> 3)) * IN_DIM + (f1 & 7);

  // X read offset for the basis consumer: row wid*16+ln, elems quad, quad+4
  const int xoff = (wid * 16 + ln) * 8 + quad;

  // B-frag LDS offsets (iter-invariant)
  int boff[2][4];
#pragma unroll
  for (int kk = 0; kk < 2; ++kk)
#pragma unroll
    for (int nt = 0; nt < 4; ++nt) {
      const int c = nt * 16 + ln;
      boff[kk][nt] = c * 64 + (((kk * 4 + quad) ^ (c & 7)) * 8);
    }

  auto issueB = [&](int kt, int st) {
    const int k0 = kt * 64;
    async_load16(bP0 + k0, &Bs[st][(wid * 16) * 64]);
    async_load16(bP1 + k0, &Bs[st][(wid * 16 + 8) * 64]);
  };
  auto issueX = [&](int kt, int st) {
    async_load4(xG0 + kt * 8, &Xs[st][wid * 128]);
    async_load4(xG1 + kt * 8, &Xs[st][wid * 128 + 64]);
  };

  // ---- prologue: X0 B0 X1 B1 X2 B2 X3 (14 DMA ops, pure-DMA stream) ------
  issueX(0, 0); issueB(0, 0);
  issueX(1, 1); issueB(1, 1);
  issueX(2, 2); issueB(2, 2);
  issueX(3, 3);
  __builtin_amdgcn_s_waitcnt(W_VM12);   // retire X0 (12 younger ops remain)
  __builtin_amdgcn_s_barrier();
  short8 afc0, afc1;
  { float xv0 = Xs[0][xoff], xv1 = Xs[0][xoff + 4];
    afc0 = basis_pack8(xv0); afc1 = basis_pack8(xv1); }

  // ---- main loop: 16 groups x 4 (ring stage compile-time) ----------------
  // Top-of-iter-k outstanding (steady, 12): B(k),X(k+1),B(k+1),X(k+2),
  // B(k+2),X(k+3) -> vm(8) retires B(k)+X(k+1). Iter issues B(k+3),X(k+4).
  for (int g = 0; g < 16; ++g) {
#pragma unroll
    for (int s = 0; s < 4; ++s) {
      const int kt = g * 4 + s;            // kt & 3 == s
      __builtin_amdgcn_s_waitcnt(W_VM8);
      __builtin_amdgcn_s_barrier();
      // x for tile k+1 (stage (s+1)&3) -- latency hides under MFMA
      float xv0 = Xs[(s + 1) & 3][xoff];
      float xv1 = Xs[(s + 1) & 3][xoff + 4];
      const int kb = (kt + 3 < NKT) ? kt + 3 : NKT - 1;
      const int kx = (kt + 4 < NKT) ? kt + 4 : NKT - 1;
      issueB(kb, (s + 3) & 3);
      issueX(kx, s);                       // (kt+4)&3 == s; stage s's x consumed
      // MFMA(k) from register A-frags + Bs ring stage s
#pragma unroll
      for (int nt = 0; nt < 4; ++nt) {
        short8 b0 = *reinterpret_cast<const short8*>(&Bs[s][boff[0][nt]]);
        acc[nt] = __builtin_amdgcn_mfma_f32_16x16x32_bf16(afc0, b0, acc[nt], 0, 0, 0);
      }
#pragma unroll
      for (int nt = 0; nt < 4; ++nt) {
        short8 b1 = *reinterpret_cast<const short8*>(&Bs[s][boff[1][nt]]);
        acc[nt] = __builtin_amdgcn_mfma_f32_16x16x32_bf16(afc1, b1, acc[nt], 0, 0, 0);
      }
      // basis for tile k+1 (off critical path; overlaps matrix pipe)
      afc0 = basis_pack8(xv0);
      afc1 = basis_pack8(xv1);
    }
  }

  // C/D layout: col = lane&15, row = quad*4 + reg  (HW-verified)
#pragma unroll
  for (int nt = 0; nt < 4; ++nt) {
    const int col = col0 + nt * 16 + ln;
#pragma unroll
    for (int r = 0; r < 4; ++r) {
      const int row = row0 + wid * 16 + quad * 4 + r;
      out[(size_t)row * OUT_DIM + col] = acc[nt][r];
    }
  }
}

// ---- fallback (no ws): on-the-fly staging, 64-tile, direct store ---------
__global__ __launch_bounds__(256, 2)
void kan_gemm_fb(const float* __restrict__ x, const float* __restrict__ coeff,
                 const float* __restrict__ scaling, float* __restrict__ out) {
  __shared__ unsigned short As[64 * 64];
  __shared__ unsigned short Bs[64 * 64];

  const int tid  = threadIdx.x;
  const int lane = tid & 63;
  const int wid  = tid >> 6;
  const int wm = wid >> 1, wn = wid & 1;
  const int ln = lane & 15, quad = lane >> 4;
  const int row0 = blockIdx.y * 64;
  const int col0 = blockIdx.x * 64;

  f32x4 acc[2][2] = {};

  for (int kt = 0; kt < KDIM / 64; ++kt) {
#pragma unroll
    for (int pp = 0; pp < 2; ++pp) {
      const int p  = tid + pp * 256;
      const int rn = p & 63;
      const int il = p >> 6;
      const int sw = ((il ^ (rn & 7)) * 8);
      short8 ha = basis_pack8(x[(size_t)(row0 + rn) * IN_DIM + kt * 8 + il]);
      *reinterpret_cast<short8*>(&As[rn * 64 + sw]) = ha;
      const float* cbase = coeff + (size_t)(kt * 8 + il) * 4096 + (size_t)(col0 + rn) * 8;
      float4 c0 = reinterpret_cast<const float4*>(cbase)[0];
      float4 c1 = reinterpret_cast<const float4*>(cbase)[1];
      float s = scaling[(size_t)(kt * 8 + il) * OUT_DIM + col0 + rn];
      short8 hb;
      hb[0] = (short)f2bf(c0.x * s); hb[1] = (short)f2bf(c0.y * s);
      hb[2] = (short)f2bf(c0.z * s); hb[3] = (short)f2bf(c0.w * s);
      hb[4] = (short)f2bf(c1.x * s); hb[5] = (short)f2bf(c1.y * s);
      hb[6] = (short)f2bf(c1.z * s); hb[7] = (short)f2bf(c1.w * s);
      *reinterpret_cast<short8*>(&Bs[rn * 64 + sw]) = hb;
    }
    __syncthreads();
#pragma unroll
    for (int kk = 0; kk < 2; ++kk) {
      short8 af[2], bfr[2];
#pragma unroll
      for (int mt = 0; mt < 2; ++mt) {
        const int r  = wm * 32 + mt * 16 + ln;
        const int pc = (kk * 4 + quad) ^ (r & 7);
        af[mt] = *reinterpret_cast<const short8*>(&As[r * 64 + pc * 8]);
      }
#pragma unroll
      for (int nt = 0; nt < 2; ++nt) {
        const int c  = wn * 32 + nt * 16 + ln;
        const int pc = (kk * 4 + quad) ^ (c & 7);
        bfr[nt] = *reinterpret_cast<const short8*>(&Bs[c * 64 + pc * 8]);
      }
#pragma unroll
      for (int mt = 0; mt < 2; ++mt)
#pragma unroll
        for (int nt = 0; nt < 2; ++nt)
          acc[mt][nt] = __builtin_amdgcn_mfma_f32_16x16x32_bf16(af[mt], bfr[nt], acc[mt][nt], 0, 0, 0);
    }
    __syncthreads();
  }
#pragma unroll
  for (int mt = 0; mt < 2; ++mt)
#pragma unroll
    for (int nt = 0; nt < 2; ++nt) {
      const int col = col0 + wn * 32 + nt * 16 + ln;
#pragma unroll
      for (int r = 0; r < 4; ++r) {
        const int row = row0 + wm * 32 + mt * 16 + quad * 4 + r;
        out[(size_t)row * OUT_DIM + col] = acc[mt][nt][r];
      }
    }
}

// ---- launch ------------------------------------------------------------
extern "C" void kernel_launch(void* const* d_in, const int* in_sizes, int n_in,
                              void* d_out, int out_size, void* d_ws, size_t ws_size,
                              hipStream_t stream) {
  const float* x       = (const float*)d_in[0];
  const float* coeff   = (const float*)d_in[1];
  const float* scaling = (const float*)d_in[2];
  float* out = (float*)d_out;

  const size_t needW = (size_t)OUT_DIM * KDIM * 2;   // 4 MB bf16 W^T

  if (ws_size >= needW) {
    unsigned short* Wt = (unsigned short*)d_ws;
    kan_prep<<<(IN_DIM * OUT_DIM) / 256, 256, 0, stream>>>(coeff, scaling, Wt);
    kan_gemm_ra<<<(BATCH / 64) * (OUT_DIM / 64), 256, 0, stream>>>(x, Wt, out);
  } else {
    kan_gemm_fb<<<dim3(OUT_DIM / 64, BATCH / 64), 256, 0, stream>>>(x, coeff, scaling, out);
  }
}